// Round 19
// baseline (170.247 us; speedup 1.0000x reference)
//
#include <hip/hip_runtime.h>
#include <math.h>

#define BB 4
#define NN 2048
#define KNN 20

typedef _Float16 f16x8 __attribute__((ext_vector_type(8)));
typedef _Float16 f16x4 __attribute__((ext_vector_type(4)));
typedef _Float16 f16x2 __attribute__((ext_vector_type(2)));
typedef float f32x4 __attribute__((ext_vector_type(4)));
typedef float f32x16 __attribute__((ext_vector_type(16)));

// Soft barrier: drain LDS ops only; global reg-loads stay in flight (their
// consumers get compiler-tracked vmcnt waits at use). "memory" clobber +
// sched_barrier(0) pin LDS ops on the correct side (guide rule #18).
__device__ __forceinline__ void soft_barrier() {
    asm volatile("s_waitcnt lgkmcnt(0)" ::: "memory");
    __builtin_amdgcn_sched_barrier(0);
    __builtin_amdgcn_s_barrier();
    __builtin_amdgcn_sched_barrier(0);
}

// ---------------------------------------------------------------------------
// KNN: one WAVE per point. LDS packed float4 {x,y,z,sq} -> b128 reads.
// ---------------------------------------------------------------------------
#define DPP_STEP(CTRL, RMASK)                                                   \
    {                                                                           \
        unsigned ov = (unsigned)__builtin_amdgcn_update_dpp(                    \
            (int)bv, (int)bv, CTRL, RMASK, 0xf, false);                         \
        unsigned oj = (unsigned)__builtin_amdgcn_update_dpp(                    \
            (int)jj, (int)jj, CTRL, RMASK, 0xf, false);                         \
        bool lt = (ov < bv) || (ov == bv && oj < jj);                           \
        bv = lt ? ov : bv;                                                      \
        jj = lt ? oj : jj;                                                      \
    }

__global__ __launch_bounds__(256) void knn_kernel(const float* __restrict__ pc,
                                                  int* __restrict__ idx_out,
                                                  float* __restrict__ rel_out) {
    __shared__ float4 sp[NN];
    const int tid = threadIdx.x;
    const int b = blockIdx.x / (NN / 4);
    const int grp = blockIdx.x % (NN / 4);
    for (int p = tid; p < NN; p += 256) {
        float x = pc[(size_t)(b * NN + p) * 6 + 0];
        float y = pc[(size_t)(b * NN + p) * 6 + 1];
        float z = pc[(size_t)(b * NN + p) * 6 + 2];
        float4 v;
        v.x = x; v.y = y; v.z = z;
        v.w = __fadd_rn(__fadd_rn(__fmul_rn(x, x), __fmul_rn(y, y)), __fmul_rn(z, z));
        sp[p] = v;
    }
    __syncthreads();
    const int lane = tid & 63;
    const int i = grp * 4 + (tid >> 6);
    const float4 pi = sp[i];
    const float xi = pi.x, yi = pi.y, zi = pi.z, sqi = pi.w;

    unsigned mmr[32];
#pragma unroll
    for (int t = 0; t < 32; ++t) {
        const int j = t * 64 + lane;
        const float4 pj = sp[j];
        float dot = __fadd_rn(__fadd_rn(__fmul_rn(xi, pj.x), __fmul_rn(yi, pj.y)),
                              __fmul_rn(zi, pj.z));
        float d2 = __fsub_rn(__fadd_rn(sqi, pj.w), __fmul_rn(2.0f, dot));
        unsigned bbits = __float_as_uint(d2);
        mmr[t] = bbits ^ (0x80000000u | (unsigned)((int)bbits >> 31));
    }

    const unsigned UMAX = 0xFFFFFFFFu;
    unsigned mask = 0u;
    unsigned v1, t1, v2, t2;

    auto refill = [&]() {
        v1 = UMAX; t1 = 0u; v2 = UMAX; t2 = 0u;
#pragma unroll
        for (int t = 0; t < 32; ++t) {
            unsigned m = ((mask >> t) & 1u) ? UMAX : mmr[t];
            bool c1 = m < v1;
            bool c2 = m < v2;
            unsigned nv2 = c1 ? v1 : (c2 ? m : v2);
            unsigned nt2 = c1 ? t1 : (c2 ? (unsigned)t : t2);
            v1 = c1 ? m : v1;
            t1 = c1 ? (unsigned)t : t1;
            v2 = nv2; t2 = nt2;
        }
    };
    refill();

    const size_t orow = (size_t)(b * NN + i);
    for (int k = 0; k < KNN; ++k) {
        unsigned bv = v1;
        unsigned jj = (t1 << 6) | (unsigned)lane;
        DPP_STEP(0x111, 0xf)
        DPP_STEP(0x112, 0xf)
        DPP_STEP(0x114, 0xf)
        DPP_STEP(0x118, 0xf)
        DPP_STEP(0x142, 0xa)
        DPP_STEP(0x143, 0xc)
        const unsigned sj = (unsigned)__builtin_amdgcn_readlane((int)jj, 63);
        if (lane == 0) {
            idx_out[orow * KNN + k] = (int)sj;
            const float4 pj = sp[sj];
            size_t ro = (orow * KNN + k) * 3;
            rel_out[ro + 0] = __fsub_rn(pj.x, xi);
            rel_out[ro + 1] = __fsub_rn(pj.y, yi);
            rel_out[ro + 2] = __fsub_rn(pj.z, zi);
        }
        if (k < KNN - 1) {
            bool am = ((sj & 63u) == (unsigned)lane);
            if (am) {
                mask |= (1u << (sj >> 6));
                v1 = v2; t1 = t2; v2 = UMAX;
            }
            if (__ballot(v1 == UMAX) != 0ull) refill();
        }
    }
}

// ---------------------------------------------------------------------------
// Taylor for ALL 4 layers in one pass; outputs f16.
// ---------------------------------------------------------------------------
__global__ __launch_bounds__(256) void taylor_all_kernel(
    const float* __restrict__ rel,
    const float* __restrict__ w10, const float* __restrict__ b10, _Float16* __restrict__ ty0,
    const float* __restrict__ w11, const float* __restrict__ b11, _Float16* __restrict__ ty1,
    const float* __restrict__ w12, const float* __restrict__ b12, _Float16* __restrict__ ty2,
    const float* __restrict__ w13, const float* __restrict__ b13, _Float16* __restrict__ ty3) {
    __shared__ float w1s[4][60];
    __shared__ float b1s[4][3];
    const int tid = threadIdx.x;
    if (tid < 240) {
        const float* wp = (tid < 60) ? w10 : (tid < 120) ? w11 : (tid < 180) ? w12 : w13;
        w1s[tid / 60][tid % 60] = wp[tid % 60];
    } else if (tid < 252) {
        int r = tid - 240;
        const float* bp = (r < 3) ? b10 : (r < 6) ? b11 : (r < 9) ? b12 : b13;
        b1s[r / 3][r % 3] = bp[r % 3];
    }
    __syncthreads();
    int t = blockIdx.x * 256 + tid;
    if (t >= BB * NN * KNN) return;
    float X = rel[(size_t)t * 3 + 0], Y = rel[(size_t)t * 3 + 1], Z = rel[(size_t)t * 3 + 2];
    float tm[20];
    tm[0] = 1.f; tm[1] = X; tm[2] = Y; tm[3] = Z;
    tm[4] = X * Y; tm[5] = X * Z; tm[6] = Y * Z;
    tm[7] = X * X; tm[8] = Y * Y; tm[9] = Z * Z;
    tm[10] = X * X * Y; tm[11] = X * X * Z; tm[12] = X * Y * Y; tm[13] = Y * Y * Z;
    tm[14] = X * Z * Z; tm[15] = Y * Z * Z; tm[16] = X * Y * Z;
    tm[17] = X * X * X; tm[18] = Y * Y * Y; tm[19] = Z * Z * Z;
    _Float16* typ[4] = {ty0, ty1, ty2, ty3};
#pragma unroll
    for (int l = 0; l < 4; ++l) {
#pragma unroll
        for (int o = 0; o < 3; ++o) {
            float a = b1s[l][o];
#pragma unroll
            for (int q = 0; q < 20; ++q) a += w1s[l][o * 20 + q] * tm[q];
            typ[l][(size_t)t * 3 + o] = (_Float16)a;
        }
    }
}

// ---------------------------------------------------------------------------
// Weight prep: w2 f32 -> f16 fragment-linear. M32: 32x32x16 frag layout.
// ---------------------------------------------------------------------------
struct WsplitArgs {
    const float* w2[4];
    _Float16* wf[4];
    int CIN[4], CPAD[4], OCB[4], KCB[4], M32[4];
    int cum[4];
};

__global__ __launch_bounds__(256) void wsplit_all_kernel(WsplitArgs a) {
    int e = blockIdx.x * 256 + threadIdx.x;
    if (e >= a.cum[3]) return;
    int l = (e >= a.cum[0]) + (e >= a.cum[1]) + (e >= a.cum[2]);
    int base = l ? a.cum[l - 1] : 0;
    e -= base;
    const int KCB = a.KCB[l], OCB = a.OCB[l], CPAD = a.CPAD[l], CIN = a.CIN[l];
    int i = e & 7;
    int lane = (e >> 3) & 63;
    int fi = e >> 9;
    int kcb = fi % KCB;
    int ocb = (fi / KCB) % OCB;
    int k = fi / (KCB * OCB);
    int oc, kk;
    if (a.M32[l]) {
        oc = ocb * 32 + (lane & 31);
        kk = kcb * 16 + (lane >> 5) * 8 + i;
    } else {
        oc = ocb * 16 + (lane & 15);
        kk = kcb * 32 + (lane >> 4) * 8 + i;
    }
    int o = kk / CPAD, c = kk % CPAD;
    float x = 0.f;
    if (o < 3 && c < CIN)
        x = a.w2[l][((size_t)oc * (CIN * 3) + c * 3 + o) * KNN + k];
    a.wf[l][e] = (_Float16)x;
}

// ---------------------------------------------------------------------------
// SpiderConv via MFMA 16x16x32 (r13 structure) — L0 (f32 pc) and L1 (f16).
// ---------------------------------------------------------------------------
template <int CIN, int COUT, int CK3P, int NT, int WM, int WN, int FM, int FN,
          int OCT, int KSPLIT, bool L0S, bool F16IN>
__global__ __launch_bounds__(256) void convm_kernel(const void* __restrict__ fin,
                                                    const int* __restrict__ idx,
                                                    const _Float16* __restrict__ tyg,
                                                    const _Float16* __restrict__ wf,
                                                    float* __restrict__ out) {
    constexpr int KR = KNN / KSPLIT;
    constexpr int SR = CK3P + 8;
    constexpr int KCB = CK3P / 32;
    constexpr int OCB = COUT / 16;
    constexpr int OCBLK = WM * FM * 16;
    constexpr int NTL = NN / NT;
    constexpr int TPR = 256 / NT;
    constexpr int CT = L0S ? 6 : (CIN / TPR);
    constexpr int CQ = L0S ? 2 : (CT >= 4 ? CT / 4 : 1);
    constexpr int GF = (CT >= 8) ? CT / 8 : 1;
    static_assert(WN * FN * 16 == NT, "n tiling");
    static_assert(OCBLK * OCT == COUT, "oc tiling");
    static_assert(WM * WN == 4, "4 waves");

    __shared__ _Float16 Bs[NT * SR];
    __shared__ _Float16 tyt[NT][3 * KR];
    __shared__ int idxt[NT][KR];

    const float* finf = (const float*)fin;
    const _Float16* finh = (const _Float16*)fin;

    const int tid = threadIdx.x;
    const int lane = tid & 63;
    const int wid = tid >> 6;
    const int wm = wid / WN;
    const int wn = wid % WN;
    int t = blockIdx.x;
    const int b = t % BB;      t /= BB;
    const int ks = t % KSPLIT; t /= KSPLIT;
    const int oct = t % OCT;   t /= OCT;
    const int ntl = t;
    const int n0 = ntl * NT;
    const int oc0 = oct * OCBLK;
    const int k0 = ks * KR;
    const size_t brow = (size_t)b * NN;

    for (int e = tid; e < NT * KR; e += 256) {
        int n = e / KR, kk = e % KR;
        idxt[n][kk] = idx[(brow + n0 + n) * KNN + k0 + kk];
    }
    for (int e = tid; e < NT * 3 * KR; e += 256) {
        int n = e / (3 * KR), q = e % (3 * KR);
        tyt[n][q] = tyg[((brow + n0 + n) * KNN + k0) * 3 + q];
    }
    __syncthreads();

    const int nrow = tid % NT;
    const int sub = tid / NT;
    float4 g[CQ];
    f16x8 gf[GF];

    auto issue_gather = [&](int kk) {
        if constexpr (L0S) {
            if (tid < 192) {
                int j = idxt[nrow][kk];
                const float* p = finf + (brow + j) * 6;
                g[0] = *reinterpret_cast<const float4*>(p);
                float2 r2 = *reinterpret_cast<const float2*>(p + 4);
                g[1].x = r2.x; g[1].y = r2.y;
            }
        } else if constexpr (F16IN) {
            int j = idxt[nrow][kk];
            const _Float16* p = finh + (brow + j) * CIN + sub * CT;
#pragma unroll
            for (int q = 0; q < GF; ++q)
                gf[q] = *reinterpret_cast<const f16x8*>(p + q * 8);
        } else {
            int j = idxt[nrow][kk];
            const float* p = finf + (brow + j) * CIN + sub * CT;
#pragma unroll
            for (int q = 0; q < CQ; ++q)
                g[q] = *reinterpret_cast<const float4*>(p + q * 4);
        }
    };
    issue_gather(0);

    f32x4 acc[FM][FN];
#pragma unroll
    for (int fm = 0; fm < FM; ++fm)
#pragma unroll
        for (int fn = 0; fn < FN; ++fn) acc[fm][fn] = (f32x4){0.f, 0.f, 0.f, 0.f};

    f16x8 areg[FM * KCB];
    auto loadA_burst = [&](int k) {
#pragma unroll
        for (int fm = 0; fm < FM; ++fm)
#pragma unroll
            for (int kcb = 0; kcb < KCB; ++kcb) {
                size_t fidx = ((size_t)k * OCB + (oc0 >> 4) + wm * FM + fm) * KCB + kcb;
                areg[fm * KCB + kcb] =
                    *reinterpret_cast<const f16x8*>(&wf[(fidx * 64 + lane) * 8]);
            }
    };

    for (int kk = 0; kk < KR; ++kk) {
        const int k = k0 + kk;
        loadA_burst(k);
        __syncthreads();
        if constexpr (L0S) {
            if (tid < 192) {
                _Float16 th = tyt[nrow][kk * 3 + sub];
                f16x2 tb; tb[0] = th; tb[1] = th;
                f16x2 g0, g1, g2;
                g0[0] = (_Float16)g[0].x; g0[1] = (_Float16)g[0].y;
                g1[0] = (_Float16)g[0].z; g1[1] = (_Float16)g[0].w;
                g2[0] = (_Float16)g[1].x; g2[1] = (_Float16)g[1].y;
                f16x2 p0 = g0 * tb, p1 = g1 * tb, p2 = g2 * tb;
                f16x8 hv;
                hv[0] = p0[0]; hv[1] = p0[1]; hv[2] = p1[0]; hv[3] = p1[1];
                hv[4] = p2[0]; hv[5] = p2[1]; hv[6] = (_Float16)0.f; hv[7] = (_Float16)0.f;
                *reinterpret_cast<f16x8*>(&Bs[nrow * SR + sub * 8]) = hv;
                if (sub == 0) {
                    f16x8 z = {};
                    *reinterpret_cast<f16x8*>(&Bs[nrow * SR + 24]) = z;
                }
            }
        } else {
            f16x2 gh[CT / 2];
            if constexpr (F16IN) {
                const f16x2* gp = reinterpret_cast<const f16x2*>(gf);
#pragma unroll
                for (int q = 0; q < CT / 2; ++q) gh[q] = gp[q];
            } else {
#pragma unroll
                for (int q = 0; q < CQ; ++q) {
                    f16x2 a0, a1;
                    a0[0] = (_Float16)g[q].x; a0[1] = (_Float16)g[q].y;
                    a1[0] = (_Float16)g[q].z; a1[1] = (_Float16)g[q].w;
                    gh[2 * q] = a0; gh[2 * q + 1] = a1;
                }
            }
            _Float16 th0 = tyt[nrow][kk * 3 + 0];
            _Float16 th1 = tyt[nrow][kk * 3 + 1];
            _Float16 th2 = tyt[nrow][kk * 3 + 2];
#pragma unroll
            for (int o = 0; o < 3; ++o) {
                _Float16 th = (o == 0) ? th0 : (o == 1) ? th1 : th2;
                f16x2 tb; tb[0] = th; tb[1] = th;
#pragma unroll
                for (int qp = 0; qp < CT / 8; ++qp) {
                    f16x2 p0 = gh[4 * qp + 0] * tb;
                    f16x2 p1 = gh[4 * qp + 1] * tb;
                    f16x2 p2 = gh[4 * qp + 2] * tb;
                    f16x2 p3 = gh[4 * qp + 3] * tb;
                    f16x8 hv;
                    hv[0] = p0[0]; hv[1] = p0[1]; hv[2] = p1[0]; hv[3] = p1[1];
                    hv[4] = p2[0]; hv[5] = p2[1]; hv[6] = p3[0]; hv[7] = p3[1];
                    *reinterpret_cast<f16x8*>(
                        &Bs[nrow * SR + o * CIN + sub * CT + qp * 8]) = hv;
                }
            }
        }
        __syncthreads();
        if (kk + 1 < KR) issue_gather(kk + 1);
#pragma unroll
        for (int kcb = 0; kcb < KCB; ++kcb) {
            f16x8 bf[FN];
#pragma unroll
            for (int fn = 0; fn < FN; ++fn) {
                int row = wn * FN * 16 + fn * 16 + (lane & 15);
                bf[fn] = *reinterpret_cast<const f16x8*>(
                    &Bs[row * SR + kcb * 32 + (lane >> 4) * 8]);
            }
#pragma unroll
            for (int fm = 0; fm < FM; ++fm)
#pragma unroll
                for (int fn = 0; fn < FN; ++fn)
                    acc[fm][fn] = __builtin_amdgcn_mfma_f32_16x16x32_f16(
                        areg[fm * KCB + kcb], bf[fn], acc[fm][fn], 0, 0, 0);
        }
    }
    float* dst = out + (size_t)ks * ((size_t)BB * NN * COUT);
#pragma unroll
    for (int fm = 0; fm < FM; ++fm) {
        const int ocb = oc0 + wm * FM * 16 + fm * 16 + ((lane >> 4) << 2);
#pragma unroll
        for (int fn = 0; fn < FN; ++fn) {
            int n = n0 + wn * FN * 16 + fn * 16 + (lane & 15);
            float4 o4;
            o4.x = acc[fm][fn][0]; o4.y = acc[fm][fn][1];
            o4.z = acc[fm][fn][2]; o4.w = acc[fm][fn][3];
            *reinterpret_cast<float4*>(&dst[(brow + n) * COUT + ocb]) = o4;
        }
    }
}

// ---------------------------------------------------------------------------
// Pipelined conv with 32x32x16 MFMA (L2/L3): 2-phase half-K pipeline.
// Soft barriers: only lgkmcnt drained at phase boundaries; global reg-loads
// stay in flight across barriers (compiler-tracked vmcnt at use).
// ---------------------------------------------------------------------------
template <int CIN, int COUT, int CK3P, int OCT, int KSPLIT>
__global__ __launch_bounds__(256) void convp32_kernel(const _Float16* __restrict__ fin,
                                                      const int* __restrict__ idx,
                                                      const _Float16* __restrict__ tyg,
                                                      const _Float16* __restrict__ wf,
                                                      float* __restrict__ out) {
    constexpr int NT = 64;
    constexpr int KR = KNN / KSPLIT;
    constexpr int SR = CK3P + 8;
    constexpr int CKH = CK3P / 2;
    constexpr int KC16 = CK3P / 16;
    constexpr int KC16H = KC16 / 2;
    constexpr int OCB32 = COUT / 32;
    constexpr int OCBLK = 128;
    constexpr int NTL = NN / NT;
    constexpr int CT = CIN / 4;
    constexpr int GF = CT / 8;
    static_assert(OCBLK * OCT == COUT, "oc tiling");
    static_assert(CKH % 16 == 0, "half alignment");

    __shared__ _Float16 Bs[NT * SR];

    const int tid = threadIdx.x;
    const int lane = tid & 63;
    const int wm = tid >> 6;
    int t = blockIdx.x;
    const int b = t % BB;      t /= BB;
    const int ks = t % KSPLIT; t /= KSPLIT;
    const int oct = t % OCT;   t /= OCT;
    const int ntl = t;
    const int n0 = ntl * NT;
    const int oc0 = oct * OCBLK;
    const int k0 = ks * KR;
    const size_t brow = (size_t)b * NN;

    const int nrow = tid % NT;
    const int sub = tid / NT;

    int idxr[KR];
    _Float16 tyr[3 * KR];
    {
        const int* ip = &idx[(brow + n0 + nrow) * KNN + k0];
#pragma unroll
        for (int kk = 0; kk < KR; ++kk) idxr[kk] = ip[kk];
        const _Float16* tp = &tyg[((brow + n0 + nrow) * KNN + k0) * 3];
#pragma unroll
        for (int q = 0; q < 3 * KR; ++q) tyr[q] = tp[q];
    }

    f16x8 gnext[GF];
    f16x2 ghc[CT / 2];

    f32x16 acc[2];
#pragma unroll
    for (int nh = 0; nh < 2; ++nh)
#pragma unroll
        for (int q = 0; q < 16; ++q) acc[nh][q] = 0.f;

    f16x8 regA[KC16H], regB[KC16H];
    auto loadA = [&](int k, int h, f16x8* dst) {
#pragma unroll
        for (int kcb = 0; kcb < KC16H; ++kcb) {
            size_t fidx = ((size_t)k * OCB32 + (oc0 >> 5) + wm) * KC16 + h * KC16H + kcb;
            dst[kcb] = *reinterpret_cast<const f16x8*>(&wf[(fidx * 64 + lane) * 8]);
        }
    };
    auto mfma_half = [&](int h, const f16x8* areg) {
#pragma unroll
        for (int kcb = 0; kcb < KC16H; ++kcb) {
            const int kabs = h * KC16H + kcb;
#pragma unroll
            for (int nh = 0; nh < 2; ++nh) {
                int row = nh * 32 + (lane & 31);
                f16x8 bf = *reinterpret_cast<const f16x8*>(
                    &Bs[row * SR + kabs * 16 + (lane >> 5) * 8]);
                acc[nh] = __builtin_amdgcn_mfma_f32_32x32x16_f16(
                    areg[kcb], bf, acc[nh], 0, 0, 0);
            }
        }
    };
    auto buildB = [&](int h, _Float16 th0, _Float16 th1, _Float16 th2) {
#pragma unroll
        for (int o = 0; o < 3; ++o) {
            const int kkpos = o * CIN + sub * CT;
            if (kkpos / CKH != h) continue;
            _Float16 th = (o == 0) ? th0 : (o == 1) ? th1 : th2;
            f16x2 tb; tb[0] = th; tb[1] = th;
#pragma unroll
            for (int qp = 0; qp < CT / 8; ++qp) {
                f16x2 p0 = ghc[4 * qp + 0] * tb;
                f16x2 p1 = ghc[4 * qp + 1] * tb;
                f16x2 p2 = ghc[4 * qp + 2] * tb;
                f16x2 p3 = ghc[4 * qp + 3] * tb;
                f16x8 hv;
                hv[0] = p0[0]; hv[1] = p0[1]; hv[2] = p1[0]; hv[3] = p1[1];
                hv[4] = p2[0]; hv[5] = p2[1]; hv[6] = p3[0]; hv[7] = p3[1];
                *reinterpret_cast<f16x8*>(&Bs[nrow * SR + kkpos + qp * 8]) = hv;
            }
        }
    };

    // ---- prologue: k = k0 ----
    {
        const _Float16* p = fin + (brow + idxr[0]) * CIN + sub * CT;
#pragma unroll
        for (int q = 0; q < GF; ++q)
            gnext[q] = *reinterpret_cast<const f16x8*>(p + q * 8);
        const f16x2* gp = reinterpret_cast<const f16x2*>(gnext);
#pragma unroll
        for (int q = 0; q < CT / 2; ++q) ghc[q] = gp[q];
    }
    loadA(k0, 0, regA);
    buildB(0, tyr[0], tyr[1], tyr[2]);
    soft_barrier();

#pragma unroll
    for (int kk = 0; kk < KR; ++kk) {
        const int k = k0 + kk;
        // phase A: MFMA h0(k) ∥ {loadA h1(k), gather(k+1), build h1(k)}
        loadA(k, 1, regB);
        if (kk + 1 < KR) {
            const _Float16* p = fin + (brow + idxr[kk + 1]) * CIN + sub * CT;
#pragma unroll
            for (int q = 0; q < GF; ++q)
                gnext[q] = *reinterpret_cast<const f16x8*>(p + q * 8);
        }
        buildB(1, tyr[kk * 3 + 0], tyr[kk * 3 + 1], tyr[kk * 3 + 2]);
        mfma_half(0, regA);
        soft_barrier();
        // phase B: MFMA h1(k) ∥ {loadA h0(k+1), commit, build h0(k+1)}
        if (kk + 1 < KR) {
            loadA(k + 1, 0, regA);
            const f16x2* gp = reinterpret_cast<const f16x2*>(gnext);
#pragma unroll
            for (int q = 0; q < CT / 2; ++q) ghc[q] = gp[q];
            buildB(0, tyr[(kk + 1) * 3 + 0], tyr[(kk + 1) * 3 + 1], tyr[(kk + 1) * 3 + 2]);
        }
        mfma_half(1, regB);
        soft_barrier();
    }

    // ---- epilogue: D col=lane&31 (n), row=(reg&3)+8*(reg>>2)+4*(lane>>5) ----
    float* dst = out + (size_t)ks * ((size_t)BB * NN * COUT);
    const int ocw = oc0 + wm * 32;
    const int hi4 = ((lane >> 5) << 2);
#pragma unroll
    for (int nh = 0; nh < 2; ++nh) {
        int n = n0 + nh * 32 + (lane & 31);
#pragma unroll
        for (int j = 0; j < 4; ++j) {
            float4 o4;
            o4.x = acc[nh][4 * j + 0];
            o4.y = acc[nh][4 * j + 1];
            o4.z = acc[nh][4 * j + 2];
            o4.w = acc[nh][4 * j + 3];
            *reinterpret_cast<float4*>(&dst[(brow + n) * COUT + ocw + j * 8 + hi4]) = o4;
        }
    }
}

// ---------------------------------------------------------------------------
// Combine k-split partials: out(f16) = relu(sum_s p[s] + bias)
// ---------------------------------------------------------------------------
template <int COUT, int KS>
__global__ __launch_bounds__(256) void combine_kernel(const float* __restrict__ p,
                                                      const float* __restrict__ b2,
                                                      _Float16* __restrict__ out) {
    constexpr size_t TOT = (size_t)BB * NN * COUT;
    size_t i = (size_t)blockIdx.x * 256 + threadIdx.x;
    if (i * 4 >= TOT) return;
    const float4* p4 = reinterpret_cast<const float4*>(p);
    float4 a = p4[i];
#pragma unroll
    for (int s = 1; s < KS; ++s) {
        float4 v = p4[i + s * (TOT / 4)];
        a.x += v.x; a.y += v.y; a.z += v.z; a.w += v.w;
    }
    float4 bb = *reinterpret_cast<const float4*>(&b2[(i * 4) % COUT]);
    f16x4 r;
    r[0] = (_Float16)fmaxf(a.x + bb.x, 0.f);
    r[1] = (_Float16)fmaxf(a.y + bb.y, 0.f);
    r[2] = (_Float16)fmaxf(a.z + bb.z, 0.f);
    r[3] = (_Float16)fmaxf(a.w + bb.w, 0.f);
    *reinterpret_cast<f16x4*>(&out[i * 4]) = r;
}

// ---------------------------------------------------------------------------
// top-2 over N per (b, channel); f1-f3 are f16; L3 fused from f32 partials.
// ---------------------------------------------------------------------------
__global__ __launch_bounds__(256) void top2_kernel(const _Float16* __restrict__ f1,
                                                   const _Float16* __restrict__ f2,
                                                   const _Float16* __restrict__ f3,
                                                   const float* __restrict__ p3,
                                                   const float* __restrict__ b23,
                                                   float* __restrict__ out) {
    __shared__ float m1s[256], m2s[256];
    const int bid = blockIdx.x;
    const int b = bid / 480;
    const int ch = bid % 480;
    const size_t brow = (size_t)b * NN;
    float m1 = -INFINITY, m2 = -INFINITY;
    if (ch < 224) {
        const _Float16* f; int C, c;
        if (ch < 32)       { f = f1; C = 32;  c = ch; }
        else if (ch < 96)  { f = f2; C = 64;  c = ch - 32; }
        else               { f = f3; C = 128; c = ch - 96; }
        for (int n = threadIdx.x; n < NN; n += 256) {
            float v = (float)f[(brow + n) * C + c];
            if (v > m1) { m2 = m1; m1 = v; }
            else if (v > m2) m2 = v;
        }
    } else {
        const int c = ch - 224;
        const float bc = b23[c];
        constexpr size_t TOT3 = (size_t)BB * NN * 256;
        for (int n = threadIdx.x; n < NN; n += 256) {
            size_t o = (brow + n) * 256 + c;
            float v = fmaxf(p3[o] + p3[TOT3 + o] + bc, 0.f);
            if (v > m1) { m2 = m1; m1 = v; }
            else if (v > m2) m2 = v;
        }
    }
    m1s[threadIdx.x] = m1; m2s[threadIdx.x] = m2;
    __syncthreads();
    for (int s = 128; s > 0; s >>= 1) {
        if (threadIdx.x < s) {
            float a1 = m1s[threadIdx.x], a2 = m2s[threadIdx.x];
            float c1 = m1s[threadIdx.x + s], c2 = m2s[threadIdx.x + s];
            m1s[threadIdx.x] = fmaxf(a1, c1);
            m2s[threadIdx.x] = fmaxf(fminf(a1, c1), fmaxf(a2, c2));
        }
        __syncthreads();
    }
    if (threadIdx.x == 0) {
        out[(size_t)b * 960 + ch * 2 + 0] = m1s[0];
        out[(size_t)b * 960 + ch * 2 + 1] = m2s[0];
    }
}

extern "C" void kernel_launch(void* const* d_in, const int* in_sizes, int n_in,
                              void* d_out, int out_size, void* d_ws, size_t ws_size,
                              hipStream_t stream) {
    const float* pc = (const float*)d_in[0];
    const float *w1[4], *b1[4], *w2[4], *b2[4];
    for (int l = 0; l < 4; ++l) {
        w1[l] = (const float*)d_in[1 + 4 * l];
        b1[l] = (const float*)d_in[2 + 4 * l];
        w2[l] = (const float*)d_in[3 + 4 * l];
        b2[l] = (const float*)d_in[4 + 4 * l];
    }
    char* ws = (char*)d_ws;
    size_t off = 0;
    auto alloc = [&](size_t bytes) -> void* {
        void* p = ws + off;
        off = (off + bytes + 255) & ~(size_t)255;
        return p;
    };
    int* idxb      = (int*)alloc((size_t)BB * NN * KNN * 4);
    float* rel     = (float*)alloc((size_t)BB * NN * KNN * 3 * 4);
    _Float16* ty0  = (_Float16*)alloc((size_t)BB * NN * KNN * 3 * 2);
    _Float16* ty1  = (_Float16*)alloc((size_t)BB * NN * KNN * 3 * 2);
    _Float16* ty2  = (_Float16*)alloc((size_t)BB * NN * KNN * 3 * 2);
    _Float16* ty3  = (_Float16*)alloc((size_t)BB * NN * KNN * 3 * 2);
    const int wtot0 = KNN * 2 * 1 * 512;
    const int wtot1 = KNN * 4 * 3 * 512;
    const int wtot2 = KNN * 4 * 12 * 512;
    const int wtot3 = KNN * 8 * 24 * 512;
    _Float16* wf0 = (_Float16*)alloc((size_t)wtot0 * 2);
    _Float16* wf1 = (_Float16*)alloc((size_t)wtot1 * 2);
    _Float16* wf2 = (_Float16*)alloc((size_t)wtot2 * 2);
    _Float16* wf3 = (_Float16*)alloc((size_t)wtot3 * 2);
    _Float16* f1  = (_Float16*)alloc((size_t)BB * NN * 32 * 2);
    _Float16* f2  = (_Float16*)alloc((size_t)BB * NN * 64 * 2);
    _Float16* f3  = (_Float16*)alloc((size_t)BB * NN * 128 * 2);
    float* pbuf   = (float*)alloc((size_t)4 * BB * NN * 128 * 4);

    knn_kernel<<<BB * NN / 4, 256, 0, stream>>>(pc, idxb, rel);

    taylor_all_kernel<<<(BB * NN * KNN + 255) / 256, 256, 0, stream>>>(
        rel, w1[0], b1[0], ty0, w1[1], b1[1], ty1, w1[2], b1[2], ty2, w1[3], b1[3], ty3);

    WsplitArgs wa;
    wa.w2[0] = w2[0]; wa.w2[1] = w2[1]; wa.w2[2] = w2[2]; wa.w2[3] = w2[3];
    wa.wf[0] = wf0; wa.wf[1] = wf1; wa.wf[2] = wf2; wa.wf[3] = wf3;
    int CINs[4] = {6, 32, 64, 128};
    int CPADs[4] = {8, 32, 64, 128};
    int OCBs[4] = {2, 4, 4, 8};
    int KCBs[4] = {1, 3, 12, 24};
    int M32s[4] = {0, 0, 1, 1};
    int cum = 0;
    for (int l = 0; l < 4; ++l) {
        wa.CIN[l] = CINs[l]; wa.CPAD[l] = CPADs[l];
        wa.OCB[l] = OCBs[l]; wa.KCB[l] = KCBs[l]; wa.M32[l] = M32s[l];
        cum += KNN * OCBs[l] * KCBs[l] * 512;
        wa.cum[l] = cum;
    }
    wsplit_all_kernel<<<(cum + 255) / 256, 256, 0, stream>>>(wa);

    // L0: f32 pc in, 16x16 MFMA
    convm_kernel<6, 32, 32, 64, 2, 2, 1, 2, 1, 4, true, false>
        <<<512, 256, 0, stream>>>(pc, idxb, ty0, wf0, pbuf);
    combine_kernel<32, 4><<<(BB * NN * 32 / 4 + 255) / 256, 256, 0, stream>>>(pbuf, b2[0], f1);

    // L1: f16 fin, 16x16 MFMA
    convm_kernel<32, 64, 96, 64, 4, 1, 1, 4, 1, 4, false, true>
        <<<512, 256, 0, stream>>>(f1, idxb, ty1, wf1, pbuf);
    combine_kernel<64, 4><<<(BB * NN * 64 / 4 + 255) / 256, 256, 0, stream>>>(pbuf, b2[1], f2);

    // L2: 32x32 pipelined + soft barriers, OCT=1, KSPLIT=4 -> grid 512
    convp32_kernel<64, 128, 192, 1, 4>
        <<<512, 256, 0, stream>>>(f2, idxb, ty2, wf2, pbuf);
    combine_kernel<128, 4><<<(BB * NN * 128 / 4 + 255) / 256, 256, 0, stream>>>(pbuf, b2[2], f3);

    // L3: 32x32 pipelined + soft barriers, OCT=2, KSPLIT=2 -> grid 512
    convp32_kernel<128, 256, 384, 2, 2>
        <<<512, 256, 0, stream>>>(f3, idxb, ty3, wf3, pbuf);

    top2_kernel<<<BB * 480, 256, 0, stream>>>(f1, f2, f3, pbuf, b2[3], (float*)d_out);
}

// Round 20
// 169.031 us; speedup vs baseline: 1.0072x; 1.0072x over previous
//
#include <hip/hip_runtime.h>
#include <math.h>

#define BB 4
#define NN 2048
#define KNN 20

typedef _Float16 f16x8 __attribute__((ext_vector_type(8)));
typedef _Float16 f16x4 __attribute__((ext_vector_type(4)));
typedef _Float16 f16x2 __attribute__((ext_vector_type(2)));
typedef float f32x4 __attribute__((ext_vector_type(4)));
typedef float f32x16 __attribute__((ext_vector_type(16)));

__device__ __forceinline__ void soft_barrier() {
    asm volatile("s_waitcnt lgkmcnt(0)" ::: "memory");
    __builtin_amdgcn_sched_barrier(0);
    __builtin_amdgcn_s_barrier();
    __builtin_amdgcn_sched_barrier(0);
}

// ---------------------------------------------------------------------------
// KNN: one WAVE per point. LDS packed float4 {x,y,z,sq} -> b128 reads.
// ---------------------------------------------------------------------------
#define DPP_STEP(CTRL, RMASK)                                                   \
    {                                                                           \
        unsigned ov = (unsigned)__builtin_amdgcn_update_dpp(                    \
            (int)bv, (int)bv, CTRL, RMASK, 0xf, false);                         \
        unsigned oj = (unsigned)__builtin_amdgcn_update_dpp(                    \
            (int)jj, (int)jj, CTRL, RMASK, 0xf, false);                         \
        bool lt = (ov < bv) || (ov == bv && oj < jj);                           \
        bv = lt ? ov : bv;                                                      \
        jj = lt ? oj : jj;                                                      \
    }

__global__ __launch_bounds__(256) void knn_kernel(const float* __restrict__ pc,
                                                  int* __restrict__ idx_out,
                                                  float* __restrict__ rel_out) {
    __shared__ float4 sp[NN];
    const int tid = threadIdx.x;
    const int b = blockIdx.x / (NN / 4);
    const int grp = blockIdx.x % (NN / 4);
    for (int p = tid; p < NN; p += 256) {
        float x = pc[(size_t)(b * NN + p) * 6 + 0];
        float y = pc[(size_t)(b * NN + p) * 6 + 1];
        float z = pc[(size_t)(b * NN + p) * 6 + 2];
        float4 v;
        v.x = x; v.y = y; v.z = z;
        v.w = __fadd_rn(__fadd_rn(__fmul_rn(x, x), __fmul_rn(y, y)), __fmul_rn(z, z));
        sp[p] = v;
    }
    __syncthreads();
    const int lane = tid & 63;
    const int i = grp * 4 + (tid >> 6);
    const float4 pi = sp[i];
    const float xi = pi.x, yi = pi.y, zi = pi.z, sqi = pi.w;

    unsigned mmr[32];
#pragma unroll
    for (int t = 0; t < 32; ++t) {
        const int j = t * 64 + lane;
        const float4 pj = sp[j];
        float dot = __fadd_rn(__fadd_rn(__fmul_rn(xi, pj.x), __fmul_rn(yi, pj.y)),
                              __fmul_rn(zi, pj.z));
        float d2 = __fsub_rn(__fadd_rn(sqi, pj.w), __fmul_rn(2.0f, dot));
        unsigned bbits = __float_as_uint(d2);
        mmr[t] = bbits ^ (0x80000000u | (unsigned)((int)bbits >> 31));
    }

    const unsigned UMAX = 0xFFFFFFFFu;
    unsigned mask = 0u;
    unsigned v1, t1, v2, t2;

    auto refill = [&]() {
        v1 = UMAX; t1 = 0u; v2 = UMAX; t2 = 0u;
#pragma unroll
        for (int t = 0; t < 32; ++t) {
            unsigned m = ((mask >> t) & 1u) ? UMAX : mmr[t];
            bool c1 = m < v1;
            bool c2 = m < v2;
            unsigned nv2 = c1 ? v1 : (c2 ? m : v2);
            unsigned nt2 = c1 ? t1 : (c2 ? (unsigned)t : t2);
            v1 = c1 ? m : v1;
            t1 = c1 ? (unsigned)t : t1;
            v2 = nv2; t2 = nt2;
        }
    };
    refill();

    const size_t orow = (size_t)(b * NN + i);
    for (int k = 0; k < KNN; ++k) {
        unsigned bv = v1;
        unsigned jj = (t1 << 6) | (unsigned)lane;
        DPP_STEP(0x111, 0xf)
        DPP_STEP(0x112, 0xf)
        DPP_STEP(0x114, 0xf)
        DPP_STEP(0x118, 0xf)
        DPP_STEP(0x142, 0xa)
        DPP_STEP(0x143, 0xc)
        const unsigned sj = (unsigned)__builtin_amdgcn_readlane((int)jj, 63);
        if (lane == 0) {
            idx_out[orow * KNN + k] = (int)sj;
            const float4 pj = sp[sj];
            size_t ro = (orow * KNN + k) * 3;
            rel_out[ro + 0] = __fsub_rn(pj.x, xi);
            rel_out[ro + 1] = __fsub_rn(pj.y, yi);
            rel_out[ro + 2] = __fsub_rn(pj.z, zi);
        }
        if (k < KNN - 1) {
            bool am = ((sj & 63u) == (unsigned)lane);
            if (am) {
                mask |= (1u << (sj >> 6));
                v1 = v2; t1 = t2; v2 = UMAX;
            }
            if (__ballot(v1 == UMAX) != 0ull) refill();
        }
    }
}

// ---------------------------------------------------------------------------
// Taylor for ALL 4 layers in one pass; outputs f16.
// ---------------------------------------------------------------------------
__global__ __launch_bounds__(256) void taylor_all_kernel(
    const float* __restrict__ rel,
    const float* __restrict__ w10, const float* __restrict__ b10, _Float16* __restrict__ ty0,
    const float* __restrict__ w11, const float* __restrict__ b11, _Float16* __restrict__ ty1,
    const float* __restrict__ w12, const float* __restrict__ b12, _Float16* __restrict__ ty2,
    const float* __restrict__ w13, const float* __restrict__ b13, _Float16* __restrict__ ty3) {
    __shared__ float w1s[4][60];
    __shared__ float b1s[4][3];
    const int tid = threadIdx.x;
    if (tid < 240) {
        const float* wp = (tid < 60) ? w10 : (tid < 120) ? w11 : (tid < 180) ? w12 : w13;
        w1s[tid / 60][tid % 60] = wp[tid % 60];
    } else if (tid < 252) {
        int r = tid - 240;
        const float* bp = (r < 3) ? b10 : (r < 6) ? b11 : (r < 9) ? b12 : b13;
        b1s[r / 3][r % 3] = bp[r % 3];
    }
    __syncthreads();
    int t = blockIdx.x * 256 + tid;
    if (t >= BB * NN * KNN) return;
    float X = rel[(size_t)t * 3 + 0], Y = rel[(size_t)t * 3 + 1], Z = rel[(size_t)t * 3 + 2];
    float tm[20];
    tm[0] = 1.f; tm[1] = X; tm[2] = Y; tm[3] = Z;
    tm[4] = X * Y; tm[5] = X * Z; tm[6] = Y * Z;
    tm[7] = X * X; tm[8] = Y * Y; tm[9] = Z * Z;
    tm[10] = X * X * Y; tm[11] = X * X * Z; tm[12] = X * Y * Y; tm[13] = Y * Y * Z;
    tm[14] = X * Z * Z; tm[15] = Y * Z * Z; tm[16] = X * Y * Z;
    tm[17] = X * X * X; tm[18] = Y * Y * Y; tm[19] = Z * Z * Z;
    _Float16* typ[4] = {ty0, ty1, ty2, ty3};
#pragma unroll
    for (int l = 0; l < 4; ++l) {
#pragma unroll
        for (int o = 0; o < 3; ++o) {
            float a = b1s[l][o];
#pragma unroll
            for (int q = 0; q < 20; ++q) a += w1s[l][o * 20 + q] * tm[q];
            typ[l][(size_t)t * 3 + o] = (_Float16)a;
        }
    }
}

// ---------------------------------------------------------------------------
// Weight prep: w2 f32 -> f16 fragment-linear. M32: 32x32x16 frag layout.
// ---------------------------------------------------------------------------
struct WsplitArgs {
    const float* w2[4];
    _Float16* wf[4];
    int CIN[4], CPAD[4], OCB[4], KCB[4], M32[4];
    int cum[4];
};

__global__ __launch_bounds__(256) void wsplit_all_kernel(WsplitArgs a) {
    int e = blockIdx.x * 256 + threadIdx.x;
    if (e >= a.cum[3]) return;
    int l = (e >= a.cum[0]) + (e >= a.cum[1]) + (e >= a.cum[2]);
    int base = l ? a.cum[l - 1] : 0;
    e -= base;
    const int KCB = a.KCB[l], OCB = a.OCB[l], CPAD = a.CPAD[l], CIN = a.CIN[l];
    int i = e & 7;
    int lane = (e >> 3) & 63;
    int fi = e >> 9;
    int kcb = fi % KCB;
    int ocb = (fi / KCB) % OCB;
    int k = fi / (KCB * OCB);
    int oc, kk;
    if (a.M32[l]) {
        oc = ocb * 32 + (lane & 31);
        kk = kcb * 16 + (lane >> 5) * 8 + i;
    } else {
        oc = ocb * 16 + (lane & 15);
        kk = kcb * 32 + (lane >> 4) * 8 + i;
    }
    int o = kk / CPAD, c = kk % CPAD;
    float x = 0.f;
    if (o < 3 && c < CIN)
        x = a.w2[l][((size_t)oc * (CIN * 3) + c * 3 + o) * KNN + k];
    a.wf[l][e] = (_Float16)x;
}

// ---------------------------------------------------------------------------
// SpiderConv via MFMA 16x16x32 (r13 structure) — L0 (f32 pc) and L1 (f16).
// ---------------------------------------------------------------------------
template <int CIN, int COUT, int CK3P, int NT, int WM, int WN, int FM, int FN,
          int OCT, int KSPLIT, bool L0S, bool F16IN>
__global__ __launch_bounds__(256) void convm_kernel(const void* __restrict__ fin,
                                                    const int* __restrict__ idx,
                                                    const _Float16* __restrict__ tyg,
                                                    const _Float16* __restrict__ wf,
                                                    float* __restrict__ out) {
    constexpr int KR = KNN / KSPLIT;
    constexpr int SR = CK3P + 8;
    constexpr int KCB = CK3P / 32;
    constexpr int OCB = COUT / 16;
    constexpr int OCBLK = WM * FM * 16;
    constexpr int NTL = NN / NT;
    constexpr int TPR = 256 / NT;
    constexpr int CT = L0S ? 6 : (CIN / TPR);
    constexpr int CQ = L0S ? 2 : (CT >= 4 ? CT / 4 : 1);
    constexpr int GF = (CT >= 8) ? CT / 8 : 1;
    static_assert(WN * FN * 16 == NT, "n tiling");
    static_assert(OCBLK * OCT == COUT, "oc tiling");
    static_assert(WM * WN == 4, "4 waves");

    __shared__ _Float16 Bs[NT * SR];
    __shared__ _Float16 tyt[NT][3 * KR];
    __shared__ int idxt[NT][KR];

    const float* finf = (const float*)fin;
    const _Float16* finh = (const _Float16*)fin;

    const int tid = threadIdx.x;
    const int lane = tid & 63;
    const int wid = tid >> 6;
    const int wm = wid / WN;
    const int wn = wid % WN;
    int t = blockIdx.x;
    const int b = t % BB;      t /= BB;
    const int ks = t % KSPLIT; t /= KSPLIT;
    const int oct = t % OCT;   t /= OCT;
    const int ntl = t;
    const int n0 = ntl * NT;
    const int oc0 = oct * OCBLK;
    const int k0 = ks * KR;
    const size_t brow = (size_t)b * NN;

    for (int e = tid; e < NT * KR; e += 256) {
        int n = e / KR, kk = e % KR;
        idxt[n][kk] = idx[(brow + n0 + n) * KNN + k0 + kk];
    }
    for (int e = tid; e < NT * 3 * KR; e += 256) {
        int n = e / (3 * KR), q = e % (3 * KR);
        tyt[n][q] = tyg[((brow + n0 + n) * KNN + k0) * 3 + q];
    }
    __syncthreads();

    const int nrow = tid % NT;
    const int sub = tid / NT;
    float4 g[CQ];
    f16x8 gf[GF];

    auto issue_gather = [&](int kk) {
        if constexpr (L0S) {
            if (tid < 192) {
                int j = idxt[nrow][kk];
                const float* p = finf + (brow + j) * 6;
                g[0] = *reinterpret_cast<const float4*>(p);
                float2 r2 = *reinterpret_cast<const float2*>(p + 4);
                g[1].x = r2.x; g[1].y = r2.y;
            }
        } else if constexpr (F16IN) {
            int j = idxt[nrow][kk];
            const _Float16* p = finh + (brow + j) * CIN + sub * CT;
#pragma unroll
            for (int q = 0; q < GF; ++q)
                gf[q] = *reinterpret_cast<const f16x8*>(p + q * 8);
        } else {
            int j = idxt[nrow][kk];
            const float* p = finf + (brow + j) * CIN + sub * CT;
#pragma unroll
            for (int q = 0; q < CQ; ++q)
                g[q] = *reinterpret_cast<const float4*>(p + q * 4);
        }
    };
    issue_gather(0);

    f32x4 acc[FM][FN];
#pragma unroll
    for (int fm = 0; fm < FM; ++fm)
#pragma unroll
        for (int fn = 0; fn < FN; ++fn) acc[fm][fn] = (f32x4){0.f, 0.f, 0.f, 0.f};

    f16x8 areg[FM * KCB];
    auto loadA_burst = [&](int k) {
#pragma unroll
        for (int fm = 0; fm < FM; ++fm)
#pragma unroll
            for (int kcb = 0; kcb < KCB; ++kcb) {
                size_t fidx = ((size_t)k * OCB + (oc0 >> 4) + wm * FM + fm) * KCB + kcb;
                areg[fm * KCB + kcb] =
                    *reinterpret_cast<const f16x8*>(&wf[(fidx * 64 + lane) * 8]);
            }
    };

    for (int kk = 0; kk < KR; ++kk) {
        const int k = k0 + kk;
        loadA_burst(k);
        __syncthreads();
        if constexpr (L0S) {
            if (tid < 192) {
                _Float16 th = tyt[nrow][kk * 3 + sub];
                f16x2 tb; tb[0] = th; tb[1] = th;
                f16x2 g0, g1, g2;
                g0[0] = (_Float16)g[0].x; g0[1] = (_Float16)g[0].y;
                g1[0] = (_Float16)g[0].z; g1[1] = (_Float16)g[0].w;
                g2[0] = (_Float16)g[1].x; g2[1] = (_Float16)g[1].y;
                f16x2 p0 = g0 * tb, p1 = g1 * tb, p2 = g2 * tb;
                f16x8 hv;
                hv[0] = p0[0]; hv[1] = p0[1]; hv[2] = p1[0]; hv[3] = p1[1];
                hv[4] = p2[0]; hv[5] = p2[1]; hv[6] = (_Float16)0.f; hv[7] = (_Float16)0.f;
                *reinterpret_cast<f16x8*>(&Bs[nrow * SR + sub * 8]) = hv;
                if (sub == 0) {
                    f16x8 z = {};
                    *reinterpret_cast<f16x8*>(&Bs[nrow * SR + 24]) = z;
                }
            }
        } else {
            f16x2 gh[CT / 2];
            if constexpr (F16IN) {
                const f16x2* gp = reinterpret_cast<const f16x2*>(gf);
#pragma unroll
                for (int q = 0; q < CT / 2; ++q) gh[q] = gp[q];
            } else {
#pragma unroll
                for (int q = 0; q < CQ; ++q) {
                    f16x2 a0, a1;
                    a0[0] = (_Float16)g[q].x; a0[1] = (_Float16)g[q].y;
                    a1[0] = (_Float16)g[q].z; a1[1] = (_Float16)g[q].w;
                    gh[2 * q] = a0; gh[2 * q + 1] = a1;
                }
            }
            _Float16 th0 = tyt[nrow][kk * 3 + 0];
            _Float16 th1 = tyt[nrow][kk * 3 + 1];
            _Float16 th2 = tyt[nrow][kk * 3 + 2];
#pragma unroll
            for (int o = 0; o < 3; ++o) {
                _Float16 th = (o == 0) ? th0 : (o == 1) ? th1 : th2;
                f16x2 tb; tb[0] = th; tb[1] = th;
#pragma unroll
                for (int qp = 0; qp < CT / 8; ++qp) {
                    f16x2 p0 = gh[4 * qp + 0] * tb;
                    f16x2 p1 = gh[4 * qp + 1] * tb;
                    f16x2 p2 = gh[4 * qp + 2] * tb;
                    f16x2 p3 = gh[4 * qp + 3] * tb;
                    f16x8 hv;
                    hv[0] = p0[0]; hv[1] = p0[1]; hv[2] = p1[0]; hv[3] = p1[1];
                    hv[4] = p2[0]; hv[5] = p2[1]; hv[6] = p3[0]; hv[7] = p3[1];
                    *reinterpret_cast<f16x8*>(
                        &Bs[nrow * SR + o * CIN + sub * CT + qp * 8]) = hv;
                }
            }
        }
        __syncthreads();
        if (kk + 1 < KR) issue_gather(kk + 1);
#pragma unroll
        for (int kcb = 0; kcb < KCB; ++kcb) {
            f16x8 bf[FN];
#pragma unroll
            for (int fn = 0; fn < FN; ++fn) {
                int row = wn * FN * 16 + fn * 16 + (lane & 15);
                bf[fn] = *reinterpret_cast<const f16x8*>(
                    &Bs[row * SR + kcb * 32 + (lane >> 4) * 8]);
            }
#pragma unroll
            for (int fm = 0; fm < FM; ++fm)
#pragma unroll
                for (int fn = 0; fn < FN; ++fn)
                    acc[fm][fn] = __builtin_amdgcn_mfma_f32_16x16x32_f16(
                        areg[fm * KCB + kcb], bf[fn], acc[fm][fn], 0, 0, 0);
        }
    }
    float* dst = out + (size_t)ks * ((size_t)BB * NN * COUT);
#pragma unroll
    for (int fm = 0; fm < FM; ++fm) {
        const int ocb = oc0 + wm * FM * 16 + fm * 16 + ((lane >> 4) << 2);
#pragma unroll
        for (int fn = 0; fn < FN; ++fn) {
            int n = n0 + wn * FN * 16 + fn * 16 + (lane & 15);
            float4 o4;
            o4.x = acc[fm][fn][0]; o4.y = acc[fm][fn][1];
            o4.z = acc[fm][fn][2]; o4.w = acc[fm][fn][3];
            *reinterpret_cast<float4*>(&dst[(brow + n) * COUT + ocb]) = o4;
        }
    }
}

// ---------------------------------------------------------------------------
// Pipelined conv with 32x32x16 MFMA, WAVES waves (WAVES*32 = COUT/OCT).
// 2-phase half-K pipeline; soft barriers; reg idx/taylor; B built ONCE per
// (ntl,k) by all WAVES*64 threads (no oct duplication when OCT==1).
// ---------------------------------------------------------------------------
template <int CIN, int COUT, int CK3P, int OCT, int KSPLIT, int WAVES>
__global__ __launch_bounds__(WAVES * 64) void convp32_kernel(
    const _Float16* __restrict__ fin,
    const int* __restrict__ idx,
    const _Float16* __restrict__ tyg,
    const _Float16* __restrict__ wf,
    float* __restrict__ out) {
    constexpr int NT = 64;
    constexpr int KR = KNN / KSPLIT;
    constexpr int SR = CK3P + 8;
    constexpr int CKH = CK3P / 2;
    constexpr int KC16 = CK3P / 16;
    constexpr int KC16H = KC16 / 2;
    constexpr int OCB32 = COUT / 32;
    constexpr int OCBLK = WAVES * 32;
    constexpr int NTL = NN / NT;
    constexpr int NTHR = WAVES * 64;
    constexpr int CT = CIN * 64 / NTHR;    // f16 per thread
    constexpr int GF = CT / 8;
    static_assert(OCBLK * OCT == COUT, "oc tiling");
    static_assert(CKH % 16 == 0, "half alignment");
    static_assert(CT % 8 == 0, "gather granule");

    __shared__ _Float16 Bs[NT * SR];

    const int tid = threadIdx.x;
    const int lane = tid & 63;
    const int wm = tid >> 6;
    int t = blockIdx.x;
    const int b = t % BB;      t /= BB;
    const int ks = t % KSPLIT; t /= KSPLIT;
    const int oct = t % OCT;   t /= OCT;
    const int ntl = t;
    const int n0 = ntl * NT;
    const int oc0 = oct * OCBLK;
    const int k0 = ks * KR;
    const size_t brow = (size_t)b * NN;

    const int nrow = tid % NT;
    const int sub = tid / NT;              // wave-uniform

    int idxr[KR];
    _Float16 tyr[3 * KR];
    {
        const int* ip = &idx[(brow + n0 + nrow) * KNN + k0];
#pragma unroll
        for (int kk = 0; kk < KR; ++kk) idxr[kk] = ip[kk];
        const _Float16* tp = &tyg[((brow + n0 + nrow) * KNN + k0) * 3];
#pragma unroll
        for (int q = 0; q < 3 * KR; ++q) tyr[q] = tp[q];
    }

    f16x8 gnext[GF];
    f16x2 ghc[CT / 2];

    f32x16 acc[2];
#pragma unroll
    for (int nh = 0; nh < 2; ++nh)
#pragma unroll
        for (int q = 0; q < 16; ++q) acc[nh][q] = 0.f;

    f16x8 regA[KC16H], regB[KC16H];
    auto loadA = [&](int k, int h, f16x8* dst) {
#pragma unroll
        for (int kcb = 0; kcb < KC16H; ++kcb) {
            size_t fidx = ((size_t)k * OCB32 + (oc0 >> 5) + wm) * KC16 + h * KC16H + kcb;
            dst[kcb] = *reinterpret_cast<const f16x8*>(&wf[(fidx * 64 + lane) * 8]);
        }
    };
    auto mfma_half = [&](int h, const f16x8* areg) {
#pragma unroll
        for (int kcb = 0; kcb < KC16H; ++kcb) {
            const int kabs = h * KC16H + kcb;
#pragma unroll
            for (int nh = 0; nh < 2; ++nh) {
                int row = nh * 32 + (lane & 31);
                f16x8 bf = *reinterpret_cast<const f16x8*>(
                    &Bs[row * SR + kabs * 16 + (lane >> 5) * 8]);
                acc[nh] = __builtin_amdgcn_mfma_f32_32x32x16_f16(
                    areg[kcb], bf, acc[nh], 0, 0, 0);
            }
        }
    };
    auto buildB = [&](int h, _Float16 th0, _Float16 th1, _Float16 th2) {
#pragma unroll
        for (int o = 0; o < 3; ++o) {
            const int kkpos = o * CIN + sub * CT;
            if (kkpos / CKH != h) continue;
            _Float16 th = (o == 0) ? th0 : (o == 1) ? th1 : th2;
            f16x2 tb; tb[0] = th; tb[1] = th;
#pragma unroll
            for (int qp = 0; qp < CT / 8; ++qp) {
                f16x2 p0 = ghc[4 * qp + 0] * tb;
                f16x2 p1 = ghc[4 * qp + 1] * tb;
                f16x2 p2 = ghc[4 * qp + 2] * tb;
                f16x2 p3 = ghc[4 * qp + 3] * tb;
                f16x8 hv;
                hv[0] = p0[0]; hv[1] = p0[1]; hv[2] = p1[0]; hv[3] = p1[1];
                hv[4] = p2[0]; hv[5] = p2[1]; hv[6] = p3[0]; hv[7] = p3[1];
                *reinterpret_cast<f16x8*>(&Bs[nrow * SR + kkpos + qp * 8]) = hv;
            }
        }
    };

    // ---- prologue: k = k0 ----
    {
        const _Float16* p = fin + (brow + idxr[0]) * CIN + sub * CT;
#pragma unroll
        for (int q = 0; q < GF; ++q)
            gnext[q] = *reinterpret_cast<const f16x8*>(p + q * 8);
        const f16x2* gp = reinterpret_cast<const f16x2*>(gnext);
#pragma unroll
        for (int q = 0; q < CT / 2; ++q) ghc[q] = gp[q];
    }
    loadA(k0, 0, regA);
    buildB(0, tyr[0], tyr[1], tyr[2]);
    soft_barrier();

#pragma unroll
    for (int kk = 0; kk < KR; ++kk) {
        const int k = k0 + kk;
        loadA(k, 1, regB);
        if (kk + 1 < KR) {
            const _Float16* p = fin + (brow + idxr[kk + 1]) * CIN + sub * CT;
#pragma unroll
            for (int q = 0; q < GF; ++q)
                gnext[q] = *reinterpret_cast<const f16x8*>(p + q * 8);
        }
        buildB(1, tyr[kk * 3 + 0], tyr[kk * 3 + 1], tyr[kk * 3 + 2]);
        mfma_half(0, regA);
        soft_barrier();
        if (kk + 1 < KR) {
            loadA(k + 1, 0, regA);
            const f16x2* gp = reinterpret_cast<const f16x2*>(gnext);
#pragma unroll
            for (int q = 0; q < CT / 2; ++q) ghc[q] = gp[q];
            buildB(0, tyr[(kk + 1) * 3 + 0], tyr[(kk + 1) * 3 + 1], tyr[(kk + 1) * 3 + 2]);
        }
        mfma_half(1, regB);
        soft_barrier();
    }

    float* dst = out + (size_t)ks * ((size_t)BB * NN * COUT);
    const int ocw = oc0 + wm * 32;
    const int hi4 = ((lane >> 5) << 2);
#pragma unroll
    for (int nh = 0; nh < 2; ++nh) {
        int n = n0 + nh * 32 + (lane & 31);
#pragma unroll
        for (int j = 0; j < 4; ++j) {
            float4 o4;
            o4.x = acc[nh][4 * j + 0];
            o4.y = acc[nh][4 * j + 1];
            o4.z = acc[nh][4 * j + 2];
            o4.w = acc[nh][4 * j + 3];
            *reinterpret_cast<float4*>(&dst[(brow + n) * COUT + ocw + j * 8 + hi4]) = o4;
        }
    }
}

// ---------------------------------------------------------------------------
// Combine k-split partials: out(f16) = relu(sum_s p[s] + bias)
// ---------------------------------------------------------------------------
template <int COUT, int KS>
__global__ __launch_bounds__(256) void combine_kernel(const float* __restrict__ p,
                                                      const float* __restrict__ b2,
                                                      _Float16* __restrict__ out) {
    constexpr size_t TOT = (size_t)BB * NN * COUT;
    size_t i = (size_t)blockIdx.x * 256 + threadIdx.x;
    if (i * 4 >= TOT) return;
    const float4* p4 = reinterpret_cast<const float4*>(p);
    float4 a = p4[i];
#pragma unroll
    for (int s = 1; s < KS; ++s) {
        float4 v = p4[i + s * (TOT / 4)];
        a.x += v.x; a.y += v.y; a.z += v.z; a.w += v.w;
    }
    float4 bb = *reinterpret_cast<const float4*>(&b2[(i * 4) % COUT]);
    f16x4 r;
    r[0] = (_Float16)fmaxf(a.x + bb.x, 0.f);
    r[1] = (_Float16)fmaxf(a.y + bb.y, 0.f);
    r[2] = (_Float16)fmaxf(a.z + bb.z, 0.f);
    r[3] = (_Float16)fmaxf(a.w + bb.w, 0.f);
    *reinterpret_cast<f16x4*>(&out[i * 4]) = r;
}

// ---------------------------------------------------------------------------
// top-2 over N per (b, channel); f1-f3 are f16; L3 fused from f32 partials.
// ---------------------------------------------------------------------------
__global__ __launch_bounds__(256) void top2_kernel(const _Float16* __restrict__ f1,
                                                   const _Float16* __restrict__ f2,
                                                   const _Float16* __restrict__ f3,
                                                   const float* __restrict__ p3,
                                                   const float* __restrict__ b23,
                                                   float* __restrict__ out) {
    __shared__ float m1s[256], m2s[256];
    const int bid = blockIdx.x;
    const int b = bid / 480;
    const int ch = bid % 480;
    const size_t brow = (size_t)b * NN;
    float m1 = -INFINITY, m2 = -INFINITY;
    if (ch < 224) {
        const _Float16* f; int C, c;
        if (ch < 32)       { f = f1; C = 32;  c = ch; }
        else if (ch < 96)  { f = f2; C = 64;  c = ch - 32; }
        else               { f = f3; C = 128; c = ch - 96; }
        for (int n = threadIdx.x; n < NN; n += 256) {
            float v = (float)f[(brow + n) * C + c];
            if (v > m1) { m2 = m1; m1 = v; }
            else if (v > m2) m2 = v;
        }
    } else {
        const int c = ch - 224;
        const float bc = b23[c];
        constexpr size_t TOT3 = (size_t)BB * NN * 256;
        for (int n = threadIdx.x; n < NN; n += 256) {
            size_t o = (brow + n) * 256 + c;
            float v = fmaxf(p3[o] + p3[TOT3 + o] + bc, 0.f);
            if (v > m1) { m2 = m1; m1 = v; }
            else if (v > m2) m2 = v;
        }
    }
    m1s[threadIdx.x] = m1; m2s[threadIdx.x] = m2;
    __syncthreads();
    for (int s = 128; s > 0; s >>= 1) {
        if (threadIdx.x < s) {
            float a1 = m1s[threadIdx.x], a2 = m2s[threadIdx.x];
            float c1 = m1s[threadIdx.x + s], c2 = m2s[threadIdx.x + s];
            m1s[threadIdx.x] = fmaxf(a1, c1);
            m2s[threadIdx.x] = fmaxf(fminf(a1, c1), fmaxf(a2, c2));
        }
        __syncthreads();
    }
    if (threadIdx.x == 0) {
        out[(size_t)b * 960 + ch * 2 + 0] = m1s[0];
        out[(size_t)b * 960 + ch * 2 + 1] = m2s[0];
    }
}

extern "C" void kernel_launch(void* const* d_in, const int* in_sizes, int n_in,
                              void* d_out, int out_size, void* d_ws, size_t ws_size,
                              hipStream_t stream) {
    const float* pc = (const float*)d_in[0];
    const float *w1[4], *b1[4], *w2[4], *b2[4];
    for (int l = 0; l < 4; ++l) {
        w1[l] = (const float*)d_in[1 + 4 * l];
        b1[l] = (const float*)d_in[2 + 4 * l];
        w2[l] = (const float*)d_in[3 + 4 * l];
        b2[l] = (const float*)d_in[4 + 4 * l];
    }
    char* ws = (char*)d_ws;
    size_t off = 0;
    auto alloc = [&](size_t bytes) -> void* {
        void* p = ws + off;
        off = (off + bytes + 255) & ~(size_t)255;
        return p;
    };
    int* idxb      = (int*)alloc((size_t)BB * NN * KNN * 4);
    float* rel     = (float*)alloc((size_t)BB * NN * KNN * 3 * 4);
    _Float16* ty0  = (_Float16*)alloc((size_t)BB * NN * KNN * 3 * 2);
    _Float16* ty1  = (_Float16*)alloc((size_t)BB * NN * KNN * 3 * 2);
    _Float16* ty2  = (_Float16*)alloc((size_t)BB * NN * KNN * 3 * 2);
    _Float16* ty3  = (_Float16*)alloc((size_t)BB * NN * KNN * 3 * 2);
    const int wtot0 = KNN * 2 * 1 * 512;
    const int wtot1 = KNN * 4 * 3 * 512;
    const int wtot2 = KNN * 4 * 12 * 512;
    const int wtot3 = KNN * 8 * 24 * 512;
    _Float16* wf0 = (_Float16*)alloc((size_t)wtot0 * 2);
    _Float16* wf1 = (_Float16*)alloc((size_t)wtot1 * 2);
    _Float16* wf2 = (_Float16*)alloc((size_t)wtot2 * 2);
    _Float16* wf3 = (_Float16*)alloc((size_t)wtot3 * 2);
    _Float16* f1  = (_Float16*)alloc((size_t)BB * NN * 32 * 2);
    _Float16* f2  = (_Float16*)alloc((size_t)BB * NN * 64 * 2);
    _Float16* f3  = (_Float16*)alloc((size_t)BB * NN * 128 * 2);
    float* pbuf   = (float*)alloc((size_t)4 * BB * NN * 128 * 4);

    knn_kernel<<<BB * NN / 4, 256, 0, stream>>>(pc, idxb, rel);

    taylor_all_kernel<<<(BB * NN * KNN + 255) / 256, 256, 0, stream>>>(
        rel, w1[0], b1[0], ty0, w1[1], b1[1], ty1, w1[2], b1[2], ty2, w1[3], b1[3], ty3);

    WsplitArgs wa;
    wa.w2[0] = w2[0]; wa.w2[1] = w2[1]; wa.w2[2] = w2[2]; wa.w2[3] = w2[3];
    wa.wf[0] = wf0; wa.wf[1] = wf1; wa.wf[2] = wf2; wa.wf[3] = wf3;
    int CINs[4] = {6, 32, 64, 128};
    int CPADs[4] = {8, 32, 64, 128};
    int OCBs[4] = {2, 4, 4, 8};
    int KCBs[4] = {1, 3, 12, 24};
    int M32s[4] = {0, 0, 1, 1};
    int cum = 0;
    for (int l = 0; l < 4; ++l) {
        wa.CIN[l] = CINs[l]; wa.CPAD[l] = CPADs[l];
        wa.OCB[l] = OCBs[l]; wa.KCB[l] = KCBs[l]; wa.M32[l] = M32s[l];
        cum += KNN * OCBs[l] * KCBs[l] * 512;
        wa.cum[l] = cum;
    }
    wsplit_all_kernel<<<(cum + 255) / 256, 256, 0, stream>>>(wa);

    // L0: f32 pc in, 16x16 MFMA
    convm_kernel<6, 32, 32, 64, 2, 2, 1, 2, 1, 4, true, false>
        <<<512, 256, 0, stream>>>(pc, idxb, ty0, wf0, pbuf);
    combine_kernel<32, 4><<<(BB * NN * 32 / 4 + 255) / 256, 256, 0, stream>>>(pbuf, b2[0], f1);

    // L1: f16 fin, 16x16 MFMA
    convm_kernel<32, 64, 96, 64, 4, 1, 1, 4, 1, 4, false, true>
        <<<512, 256, 0, stream>>>(f1, idxb, ty1, wf1, pbuf);
    combine_kernel<64, 4><<<(BB * NN * 64 / 4 + 255) / 256, 256, 0, stream>>>(pbuf, b2[1], f2);

    // L2: 32x32 pipelined, 4 waves, OCT=1, KSPLIT=4 -> grid 512
    convp32_kernel<64, 128, 192, 1, 4, 4>
        <<<512, 256, 0, stream>>>(f2, idxb, ty2, wf2, pbuf);
    combine_kernel<128, 4><<<(BB * NN * 128 / 4 + 255) / 256, 256, 0, stream>>>(pbuf, b2[2], f3);

    // L3: 32x32 pipelined, 8 waves (512 thr), OCT=1, KSPLIT=2 -> grid 256,
    // B built ONCE per (ntl,k): B-writes + gather traffic halved vs OCT=2.
    convp32_kernel<128, 256, 384, 1, 2, 8>
        <<<256, 512, 0, stream>>>(f3, idxb, ty3, wf3, pbuf);

    top2_kernel<<<BB * 480, 256, 0, stream>>>(f1, f2, f3, pbuf, b2[3], (float*)d_out);
}